// Round 9
// baseline (28.227 us; speedup 1.0000x reference)
//
#include <hip/hip_runtime.h>

typedef float  f32x4  __attribute__((ext_vector_type(4)));
typedef short  short8 __attribute__((ext_vector_type(8)));

#define STRIP  16      // output rows per block
#define HALO_R 18
#define HALO_C 66
#define ROWP   68      // padded x-extent of LDS feature arrays

__device__ __forceinline__ unsigned f2bf(float f) {
    unsigned u = __builtin_bit_cast(unsigned, f);
    u = u + 0x7FFFu + ((u >> 16) & 1u);        // RNE to bf16
    return u >> 16;
}

__device__ __forceinline__ short8 pack8(const float* w) {
    union { unsigned u[4]; short8 s; } z;
    #pragma unroll
    for (int k = 0; k < 4; ++k)
        z.u[k] = f2bf(w[2 * k]) | (f2bf(w[2 * k + 1]) << 16);
    return z.s;
}

// Block = one 16-row output strip of one (b,c) plane; 4 waves, 256 threads.
// Phase 1: stage dense features in LDS: Fs[y][x][g0..7] bf16 (basis values),
//          Fb[y][x] f32 (silu), halo coords y in [0,18), x in [0,66).
// Phase 2: spline path via mfma_f32_16x16x32_bf16:
//          C[n][p] = sum_k A[n][k] B[k][p], k = tap*8+g (72 used, 96 padded).
//          B-fragment = one ds_read_b128 (8 contiguous basis values of the
//          lane's tap-shifted pixel). Base path = VALU FMA vs bw.
__global__ __launch_bounds__(256, 2) void kan_conv_kernel(
    const float* __restrict__ x,     // (256, 64, 64)
    const float* __restrict__ bw,    // (8, 9)
    const float* __restrict__ sw,    // (8, 9, 8)
    const float* __restrict__ ss,    // (8, 9)
    float* __restrict__ out)         // (256, 8, 64, 64)
{
    __shared__ __align__(16) unsigned short Fs[HALO_R * ROWP * 8];
    __shared__ float Fb[HALO_R * ROWP];

    const int tid  = threadIdx.x;
    const int lane = tid & 63;
    const int wv   = tid >> 6;
    const int p    = lane & 15;     // pixel within tile / A row n
    const int cc   = lane >> 4;     // k-chunk / C row block
    const int bc   = blockIdx.x >> 2;
    const int r0   = (blockIdx.x & 3) * STRIP;

    const float* __restrict__ xin = x + (size_t)bc * 4096;

    // ---- per-lane constant fragments (global reads, cached) ----
    // A-fragments: n = lane&15, k-chunk cc: step s<2 -> tap = s*4+cc; s=2 -> tap 8 (cc==0).
    const int n  = p;
    const int nc = (n < 8) ? n : 0;
    short8 Af[3];
    #pragma unroll
    for (int s = 0; s < 3; ++s) {
        const int tap = (s < 2) ? (s * 4 + cc) : 8;
        const bool ok = (n < 8) && (s < 2 || cc == 0);
        float w8[8];
        #pragma unroll
        for (int g = 0; g < 8; ++g)
            w8[g] = ok ? sw[(nc * 9 + tap) * 8 + g] * ss[nc * 9 + tap] : 0.f;
        Af[s] = pack8(w8);
    }
    // base weights: rows nb..nb+3 (cc<2 real, cc>=2 harmless duplicates)
    const int nb = (cc < 2) ? cc * 4 : 0;
    float bwr[4][9];
    #pragma unroll
    for (int r = 0; r < 4; ++r)
        #pragma unroll
        for (int t = 0; t < 9; ++t)
            bwr[r][t] = bw[(nb + r) * 9 + t];

    // ---- phase 1: feature staging ----
    for (int q = tid; q < HALO_R * HALO_C; q += 256) {
        const int y  = q / HALO_C;
        const int xx = q - y * HALO_C;
        const int gy = r0 + y - 1;
        const int gx = xx - 1;
        const bool inb = ((unsigned)gy < 64u) & ((unsigned)gx < 64u);
        const float v = inb ? xin[gy * 64 + gx] : 0.f;

        const float s = __fdividef(v, 1.f + __expf(-v));   // silu

        float u  = (v + 2.2f) * 2.5f;
        float mf = floorf(u);
        float t  = u - mf;
        int   m  = (int)mf;
        const bool inr = (m >= 0) && (m <= 10);
        float t2 = t * t, t3 = t2 * t, omt = 1.f - t;
        const float c6 = 1.f / 6.f;
        float wr0 = c6 * omt * omt * omt;
        float wr1 = c6 * (3.f * t3 - 6.f * t2 + 4.f);
        float wr2 = c6 * (-3.f * t3 + 3.f * t2 + 3.f * t + 1.f);
        float wr3 = c6 * t3;
        if (!inr) { wr0 = 0.f; wr1 = 0.f; wr2 = 0.f; wr3 = 0.f; }

        const int base = m - 3;
        float den[8];
        #pragma unroll
        for (int g = 0; g < 8; ++g) {
            const int r = g - base;
            float val = 0.f;
            val = (r == 0) ? wr0 : val;
            val = (r == 1) ? wr1 : val;
            val = (r == 2) ? wr2 : val;
            val = (r == 3) ? wr3 : val;
            den[g] = val;
        }

        union { unsigned u4[4]; uint4 v4; } pk;
        #pragma unroll
        for (int k = 0; k < 4; ++k)
            pk.u4[k] = f2bf(den[2 * k]) | (f2bf(den[2 * k + 1]) << 16);
        *(uint4*)&Fs[(y * ROWP + xx) * 8] = pk.v4;
        Fb[y * ROWP + xx] = s;
    }
    __syncthreads();

    // ---- phase 2: GEMM over 64 tiles (16 rows x 4 col-blocks) ----
    float* __restrict__ obase = out + (size_t)bc * (8 * 4096);
    const short8 zf = {};

    for (int tau = wv; tau < 64; tau += 4) {
        const int orow = tau >> 2;
        const int colb = tau & 3;
        const int px   = colb * 16 + p;

        // B-fragments: one b128 per step (lane's tap at its pixel)
        short8 Bf[3];
        #pragma unroll
        for (int s = 0; s < 3; ++s) {
            const int tap = (s < 2) ? (s * 4 + cc) : 8;
            const bool ok = (s < 2) || (cc == 0);
            const int di = tap / 3, dj = tap % 3;
            const short8 ld = *(const short8*)&Fs[((orow + di) * ROWP + px + dj) * 8];
            Bf[s] = ok ? ld : zf;
        }

        f32x4 acc = {0.f, 0.f, 0.f, 0.f};
        acc = __builtin_amdgcn_mfma_f32_16x16x32_bf16(Af[0], Bf[0], acc, 0, 0, 0);
        acc = __builtin_amdgcn_mfma_f32_16x16x32_bf16(Af[1], Bf[1], acc, 0, 0, 0);
        acc = __builtin_amdgcn_mfma_f32_16x16x32_bf16(Af[2], Bf[2], acc, 0, 0, 0);

        // base path: 9 silu reads + 36 FMA
        float bacc[4] = {0.f, 0.f, 0.f, 0.f};
        #pragma unroll
        for (int di = 0; di < 3; ++di)
            #pragma unroll
            for (int dj = 0; dj < 3; ++dj) {
                const float sv = Fb[(orow + di) * ROWP + px + dj];
                const int t = di * 3 + dj;
                #pragma unroll
                for (int r = 0; r < 4; ++r)
                    bacc[r] += sv * bwr[r][t];
            }

        if (cc < 2) {
            float* o = obase + (size_t)(r0 + orow) * 64 + colb * 16 + p;
            #pragma unroll
            for (int r = 0; r < 4; ++r)
                o[(cc * 4 + r) * 4096] = acc[r] + bacc[r];
        }
    }
}

extern "C" void kernel_launch(void* const* d_in, const int* in_sizes, int n_in,
                              void* d_out, int out_size, void* d_ws, size_t ws_size,
                              hipStream_t stream) {
    const float* x  = (const float*)d_in[0];
    const float* bw = (const float*)d_in[1];
    const float* sw = (const float*)d_in[2];
    const float* ss = (const float*)d_in[3];
    float* out = (float*)d_out;

    dim3 block(256, 1, 1);
    dim3 grid(1024, 1, 1);   // 256 bc-planes x 4 strips
    hipLaunchKernelGGL(kan_conv_kernel, grid, block, 0, stream, x, bw, sw, ss, out);
}